// Round 1
// baseline (77.812 us; speedup 1.0000x reference)
//
#include <hip/hip_runtime.h>

// out = F_amp(MLP(z_i, z_j, sep_xy2)) * (dxy / sep_r2)
// 2 elements per thread: 3x float4 loads (48B), 1x float4 store (16B).

__device__ __forceinline__ float lrelu(float x) {
    // alpha = 0.1: max(x, 0.1x) == leaky_relu for all x
    return fmaxf(x, 0.1f * x);
}

__device__ __forceinline__ float tanh_fast(float x) {
    // tanh(x) = 1 - 2/(exp(2x)+1); native v_exp + v_rcp, ~1e-6 rel err.
    // Large |x| limits are exact: exp->inf => 1-0, exp->0 => 1-2.
    float e = __expf(2.0f * x);
    return 1.0f - 2.0f * __builtin_amdgcn_rcpf(e + 1.0f);
}

__global__ void __launch_bounds__(256) fused_mlp_kernel(
    const float* __restrict__ in,
    const float* __restrict__ W1, const float* __restrict__ b1,
    const float* __restrict__ W2, const float* __restrict__ b2,
    const float* __restrict__ W3, const float* __restrict__ b3,
    const float* __restrict__ W4, const float* __restrict__ b4,
    float* __restrict__ out, int npairs)
{
    int p = blockIdx.x * blockDim.x + threadIdx.x;
    if (p >= npairs) return;

    const float4* in4 = reinterpret_cast<const float4*>(in);
    float4 A = in4[3 * p + 0];
    float4 Bv = in4[3 * p + 1];
    float4 Cv = in4[3 * p + 2];

    float x[2][6] = {
        {A.x, A.y, A.z, A.w, Bv.x, Bv.y},
        {Bv.z, Bv.w, Cv.x, Cv.y, Cv.z, Cv.w}
    };

    float o[4];

    #pragma unroll
    for (int e = 0; e < 2; ++e) {
        float dx = x[e][3] - x[e][0];
        float dy = x[e][4] - x[e][1];
        float dz = x[e][5] - x[e][2];
        float sep_xy2 = fmaf(dx, dx, dy * dy);
        float sep_r2  = fmaf(dz, dz, sep_xy2);
        float inv_r2  = __builtin_amdgcn_rcpf(sep_r2);

        float z0 = x[e][2];   // z_i
        float z1 = x[e][5];   // z_j
        float z2 = sep_xy2;   // sep_xy^2

        // Layer 1: [3] x [3,10], leaky relu
        float h1[10];
        #pragma unroll
        for (int j = 0; j < 10; ++j) {
            float a = b1[j];
            a = fmaf(z0, W1[0 * 10 + j], a);
            a = fmaf(z1, W1[1 * 10 + j], a);
            a = fmaf(z2, W1[2 * 10 + j], a);
            h1[j] = lrelu(a);
        }

        // Layer 2: [10] x [10,10], tanh
        float h2[10];
        #pragma unroll
        for (int j = 0; j < 10; ++j) {
            float a = b2[j];
            #pragma unroll
            for (int i = 0; i < 10; ++i) a = fmaf(h1[i], W2[i * 10 + j], a);
            h2[j] = tanh_fast(a);
        }

        // Layer 3: [10] x [10,10], leaky relu
        float h3[10];
        #pragma unroll
        for (int j = 0; j < 10; ++j) {
            float a = b3[j];
            #pragma unroll
            for (int i = 0; i < 10; ++i) a = fmaf(h2[i], W3[i * 10 + j], a);
            h3[j] = lrelu(a);
        }

        // Layer 4: [10] x [10,1]
        float f = b4[0];
        #pragma unroll
        for (int i = 0; i < 10; ++i) f = fmaf(h3[i], W4[i], f);

        float s = f * inv_r2;
        o[2 * e + 0] = s * dx;
        o[2 * e + 1] = s * dy;
    }

    reinterpret_cast<float4*>(out)[p] = make_float4(o[0], o[1], o[2], o[3]);
}

extern "C" void kernel_launch(void* const* d_in, const int* in_sizes, int n_in,
                              void* d_out, int out_size, void* d_ws, size_t ws_size,
                              hipStream_t stream) {
    const float* in = (const float*)d_in[0];
    const float* W1 = (const float*)d_in[1];
    const float* b1 = (const float*)d_in[2];
    const float* W2 = (const float*)d_in[3];
    const float* b2 = (const float*)d_in[4];
    const float* W3 = (const float*)d_in[5];
    const float* b3 = (const float*)d_in[6];
    const float* W4 = (const float*)d_in[7];
    const float* b4 = (const float*)d_in[8];
    float* out = (float*)d_out;

    int npairs = out_size / 4;          // 2 elements (4 output floats) per thread
    int blocks = (npairs + 255) / 256;
    fused_mlp_kernel<<<blocks, 256, 0, stream>>>(
        in, W1, b1, W2, b2, W3, b3, W4, b4, out, npairs);
}